// Round 17
// baseline (181.313 us; speedup 1.0000x reference)
//
#include <hip/hip_runtime.h>
#include <math.h>

constexpr int kH = 64, kW = 128, kB = 2, kS = 4;
constexpr int kNP = kH * kW;          // 8192 points per set
constexpr int kPairs = kB * kS;       // 8
constexpr int kDirs = kPairs * 2;     // 16
constexpr float kPi = 3.14159265358979323846f;
constexpr float kFovUp = 3.0f * kPi / 180.0f;
constexpr float kFovDown = -25.0f * kPi / 180.0f;

typedef short short8 __attribute__((ext_vector_type(8)));
typedef unsigned short ushort8 __attribute__((ext_vector_type(8)));
typedef float floatx4 __attribute__((ext_vector_type(4)));

// nn: mfma_f32_16x16x32_bf16 + fminf folds + fence-free ticket (R12 anchor)
// on COMPACTED sets, with PRECOMPUTED candidate F-records read directly from
// global (L2) — no LDS staging, no __syncthreads in the hot path.
// R16 post-mortem: per-block LDS staging + per-block query conversion made
// 16-ctile blocks overhead-dominated (MfmaUtil 6%).
constexpr int NCC = 32;               // candidate chunks of 256
constexpr int CCH = 256;
constexpr int NQB = 16;               // query blocks of 512
// grid = 16 * 16 * 32 = 8192 blocks, 512 per dir.

// ws layout (float offsets) — 6.8 MB total (R5-proven footprint)
// cpts : [kDirs][kNP] float4   -> 524288 @ 0       (2 MB)
// min  : [kDirs][kNP] u32      -> 131072 @ 524288  (0.5 MB; prep inits 0xFF)
// frec : [kDirs][kNP] 2xushort8-> 1048576 @ 655360 (4 MB)
// cnt  : [16] u32 @ 1703936 \
// dcnt : [16] u32 @ 1703952  > zeroed by one tiny hipMemsetAsync (132 B)
// acnt : u32      @ 1703968 /
// mval : [16] f32 @ 1703984
constexpr size_t OFF_MIN = 524288;
constexpr size_t OFF_FREC = 655360;
constexpr size_t OFF_CNT = 1703936;
constexpr size_t OFF_DCNT = 1703952;
constexpr size_t OFF_ACNT = 1703968;
constexpr size_t OFF_MVAL = 1703984;

__device__ __forceinline__ unsigned short f2bf(float v) {
  unsigned u = __float_as_uint(v);
  unsigned r = u + 0x7FFFu + ((u >> 16) & 1u);   // RNE
  return (unsigned short)(r >> 16);
}
__device__ __forceinline__ float bf2f(unsigned short b) {
  return __uint_as_float(((unsigned)b) << 16);
}

// Candidate record F (16 bf16; K-quads: q0=k0..7, q1=k8..15, q2/q3 unused —
// B is zero there so A content is irrelevant) pairs with query record G:
//  k : 0    1    2    3    4    5    6    7  | 8    9    10   11   12-15
//  F : Xh   Xl   Xh   Yh   Yl   Yh   Zh   Zl | Zh   Ch   Cl   Cl2  0
//  G : xh   xh   xl   yh   yh   yl   zh   zh | zl   1    1    1    0
// sum_k F*G = X*x + Y*y + Z*z + ct  (drops only lo*lo terms ~2e-4)

__global__ __launch_bounds__(256) void prep_kernel(
    const float* __restrict__ rv, const float* __restrict__ tgt,
    float4* __restrict__ cpts, ushort8* __restrict__ frec,
    unsigned* __restrict__ minarr, unsigned* __restrict__ cnt) {
  // Block-level compacted append: ONE global atomicAdd per block per counter
  __shared__ unsigned wtot[2][4];
  __shared__ unsigned sbase[2];

  int idx = blockIdx.x * 256 + threadIdx.x;   // [0, kPairs*kNP)
  int p = idx >> 13;                          // block-uniform (32 blocks/pair)
  int k = idx & (kNP - 1);
  int h = k >> 7;
  int w = k & 127;
  int t = threadIdx.x;
  int lane = t & 63, wave = t >> 6;

  float r = rv[idx];
  float pitch = (1.0f - (h + 0.5f) * (1.0f / kH)) * (kFovUp - kFovDown) + kFovDown;
  float yaw = -(((w + 0.5f) * (1.0f / kW)) * 2.0f - 1.0f) * kPi;
  float cp = __cosf(pitch), sp = __sinf(pitch);
  float cy = __cosf(yaw), sy = __sinf(yaw);
  float px = r * cp * cy, py = r * cp * sy, pz = r * sp;

  const float* tb = tgt + (size_t)p * 4 * kNP;
  float tv = tb[k];
  float tx = tb[kNP + k], ty = tb[2 * kNP + k], tz = tb[3 * kNP + k];

  float no = px * px + py * py + pz * pz;
  float nt = tx * tx + ty * ty + tz * tz;

  int d0 = 2 * p, d1 = d0 + 1;
  unsigned long long lt = (1ull << lane) - 1ull;

  bool v0 = (r > 0.0f);
  unsigned long long m0 = __ballot(v0);
  int pre0 = __popcll(m0 & lt);
  bool v1 = (tv > 0.0f);
  unsigned long long m1 = __ballot(v1);
  int pre1 = __popcll(m1 & lt);
  if (lane == 0) {
    wtot[0][wave] = (unsigned)__popcll(m0);
    wtot[1][wave] = (unsigned)__popcll(m1);
  }
  __syncthreads();
  unsigned woff0 = 0, woff1 = 0, tot0 = 0, tot1 = 0;
#pragma unroll
  for (int ww = 0; ww < 4; ++ww) {
    unsigned a0 = wtot[0][ww], a1 = wtot[1][ww];
    if (ww < wave) { woff0 += a0; woff1 += a1; }
    tot0 += a0; tot1 += a1;
  }
  if (t == 0) {
    sbase[0] = tot0 ? atomicAdd(&cnt[d0], tot0) : 0u;
    sbase[1] = tot1 ? atomicAdd(&cnt[d1], tot1) : 0u;
  }
  __syncthreads();
  if (v0) {
    size_t pos = (size_t)d0 * kNP + sbase[0] + woff0 + pre0;
    cpts[pos] = make_float4(px, py, pz, no);
    float X = -2.0f * px, Y = -2.0f * py, Z = -2.0f * pz;
    unsigned short Xh = f2bf(X), Yh = f2bf(Y), Zh = f2bf(Z);
    unsigned short Xl = f2bf(X - bf2f(Xh));
    unsigned short Yl = f2bf(Y - bf2f(Yh));
    unsigned short Zl = f2bf(Z - bf2f(Zh));
    unsigned short Ch = f2bf(no);
    float c1 = no - bf2f(Ch);
    unsigned short Cl = f2bf(c1);
    unsigned short Cl2 = f2bf(c1 - bf2f(Cl));
    frec[pos * 2] = (ushort8){Xh, Xl, Xh, Yh, Yl, Yh, Zh, Zl};
    frec[pos * 2 + 1] = (ushort8){Zh, Ch, Cl, Cl2, 0, 0, 0, 0};
  }
  if (v1) {
    size_t pos = (size_t)d1 * kNP + sbase[1] + woff1 + pre1;
    cpts[pos] = make_float4(tx, ty, tz, nt);
    float X = -2.0f * tx, Y = -2.0f * ty, Z = -2.0f * tz;
    unsigned short Xh = f2bf(X), Yh = f2bf(Y), Zh = f2bf(Z);
    unsigned short Xl = f2bf(X - bf2f(Xh));
    unsigned short Yl = f2bf(Y - bf2f(Yh));
    unsigned short Zl = f2bf(Z - bf2f(Zh));
    unsigned short Ch = f2bf(nt);
    float c1 = nt - bf2f(Ch);
    unsigned short Cl = f2bf(c1);
    unsigned short Cl2 = f2bf(c1 - bf2f(Cl));
    frec[pos * 2] = (ushort8){Xh, Xl, Xh, Yh, Yl, Yh, Zh, Zl};
    frec[pos * 2 + 1] = (ushort8){Zh, Ch, Cl, Cl2, 0, 0, 0, 0};
  }
  minarr[(size_t)d0 * kNP + k] = 0xFFFFFFFFu;
  minarr[(size_t)d1 * kNP + k] = 0xFFFFFFFFu;
}

__global__ __launch_bounds__(256, 4) void nn_kernel(
    const float4* __restrict__ cpts, const ushort8* __restrict__ frec,
    unsigned* __restrict__ minarr, const unsigned* __restrict__ cnt,
    float* __restrict__ mval, unsigned* __restrict__ dcnt,
    unsigned* __restrict__ acnt, float* __restrict__ out) {
  __shared__ unsigned s_ticket;
  __shared__ float sw[4];

  int bid = blockIdx.x;
  int d = bid >> 9;            // 512 blocks per dir
  int rem = bid & 511;
  int qb = rem >> 5;           // / NCC
  int ch = rem & 31;
  int t = threadIdx.x;

  int cntq = (int)cnt[d];       // valid queries of this dir
  int cntc = (int)cnt[d ^ 1];   // valid candidates = partner dir's points
  int cbase = ch * CCH;
  bool active = (qb * 512 < cntq) && (cbase < cntc);

  if (active) {
    int wave = t >> 6, lane = t & 63;
    int n = lane & 15, q = lane >> 4;    // q = K-quad (HW-verified layout)
    int qbase = d * kNP + qb * 512 + wave * 128;

    const short one_bf = (short)0x3F80;  // bf16(1.0)
    short8 bfr[8];
    float mn[8];
#pragma unroll
    for (int i = 0; i < 8; ++i) {
      short8 b = (short8){0, 0, 0, 0, 0, 0, 0, 0};
      if (q < 2) {
        // reads past cntq hit poison floats — harmless, their minarr slots
        // are never read by the reducer.
        float4 P = cpts[qbase + i * 16 + n];
        unsigned short xh = f2bf(P.x), yh = f2bf(P.y), zh = f2bf(P.z);
        unsigned short xl = f2bf(P.x - bf2f(xh));
        unsigned short yl = f2bf(P.y - bf2f(yh));
        unsigned short zl = f2bf(P.z - bf2f(zh));
        if (q == 0)
          b = (short8){(short)xh, (short)xh, (short)xl, (short)yh,
                       (short)yh, (short)yl, (short)zh, (short)zh};
        else
          b = (short8){(short)zl, one_bf, one_bf, one_bf, 0, 0, 0, 0};
      }
      bfr[i] = b;
      mn[i] = 3.0e38f;
    }

    floatx4 zc = {0.0f, 0.0f, 0.0f, 0.0f};
    // Tail-pad slice: rows past cntc must evaluate to +32768 (excluded).
    // q1 K-slice {0, Ch=bf16(32768), 0,...} x G-hi {zl,1,1,1,...} = 32768;
    // q0 slice all-zero x G-lo = 0. q>=2: B is zero, A irrelevant.
    ushort8 pad = (ushort8){0, 0, 0, 0, 0, 0, 0, 0};
    if (q & 1) pad[1] = (unsigned short)0x4700;  // bf16(32768)

    const ushort8* fr = frec + (size_t)(d ^ 1) * kNP * 2 + (q & 1);
    int nct = (cntc - cbase + 15) >> 4;
    if (nct > CCH / 16) nct = CCH / 16;
#pragma unroll 2
    for (int ctile = 0; ctile < nct; ++ctile) {
      int cidx = cbase + ctile * 16 + n;
      ushort8 av = fr[(size_t)cidx * 2];   // direct global (L2-hot) A-load
      if (cidx >= cntc) av = pad;          // tail guard (last tile only)
      short8 a = *(short8*)&av;
#pragma unroll
      for (int i = 0; i < 8; ++i) {
        floatx4 dr = __builtin_amdgcn_mfma_f32_16x16x32_bf16(a, bfr[i], zc, 0, 0, 0);
        float u = fminf(fminf(dr[0], dr[1]), dr[2]);
        mn[i] = fminf(fminf(u, dr[3]), mn[i]);
      }
    }

#pragma unroll
    for (int i = 0; i < 8; ++i) {
      float m = mn[i];
      m = fminf(m, __shfl_xor(m, 16));
      m = fminf(m, __shfl_xor(m, 32));
      if (lane < 16) {
        unsigned bb = __float_as_uint(m);
        unsigned e = (bb & 0x80000000u) ? ~bb : (bb | 0x80000000u);
        atomicMin(&minarr[qbase + i * 16 + lane], e);
      }
    }
  }

  // ---- ticket: last block of this dir reduces (fence-free, R12-proven) ----
  __syncthreads();
  if (t == 0)
    s_ticket = __hip_atomic_fetch_add(&dcnt[d], 1u, __ATOMIC_RELAXED,
                                      __HIP_MEMORY_SCOPE_AGENT);
  __syncthreads();
  if (s_ticket != (unsigned)(NQB * NCC - 1)) return;

  float wsum = 0.0f;
#pragma unroll 4
  for (int j = 0; j < 32; ++j) {
    int k = j * 256 + t;
    if (k < cntq) {
      unsigned u = __hip_atomic_load(&minarr[(size_t)d * kNP + k],
                                     __ATOMIC_RELAXED, __HIP_MEMORY_SCOPE_AGENT);
      unsigned bb = (u & 0x80000000u) ? (u ^ 0x80000000u) : ~u;
      wsum += cpts[(size_t)d * kNP + k].w + __uint_as_float(bb);
    }
  }
#pragma unroll
  for (int off = 32; off; off >>= 1) wsum += __shfl_down(wsum, off);
  if ((t & 63) == 0) sw[t >> 6] = wsum;
  __syncthreads();
  if (t == 0) {
    float ws_ = sw[0] + sw[1] + sw[2] + sw[3];
    __hip_atomic_store(&mval[d], ws_ / fmaxf((float)cntq, 1.0f),
                       __ATOMIC_RELAXED, __HIP_MEMORY_SCOPE_AGENT);
    s_ticket = __hip_atomic_fetch_add(acnt, 1u, __ATOMIC_ACQ_REL,
                                      __HIP_MEMORY_SCOPE_AGENT);
  }
  __syncthreads();
  if (s_ticket != (unsigned)(kDirs - 1)) return;
  // ---- very last block combines 16 dir values into the 12 outputs ----
  if (t == 0) {
    float mv[kDirs];
    for (int dd = 0; dd < kDirs; ++dd)
      mv[dd] = __hip_atomic_load(&mval[dd], __ATOMIC_RELAXED,
                                 __HIP_MEMORY_SCOPE_AGENT);
    for (int s = 0; s < kS; ++s) {
      float acc = 0.0f;
      for (int b = 0; b < kB; ++b) {
        int p = b * kS + s;
        float tens = mv[2 * p] + mv[2 * p + 1];
        out[kS + s * kB + b] = tens;
        acc += tens;
      }
      out[s] = acc * (1.0f / kB);
    }
  }
}

extern "C" void kernel_launch(void* const* d_in, const int* in_sizes, int n_in,
                              void* d_out, int out_size, void* d_ws, size_t ws_size,
                              hipStream_t stream) {
  const float* rv = (const float*)d_in[0];
  const float* tgt = (const float*)d_in[1];
  float* ws = (float*)d_ws;
  float4* cpts = (float4*)ws;
  unsigned* minarr = (unsigned*)(ws + OFF_MIN);
  ushort8* frec = (ushort8*)(ws + OFF_FREC);
  unsigned* cnt = (unsigned*)(ws + OFF_CNT);
  unsigned* dcnt = (unsigned*)(ws + OFF_DCNT);
  unsigned* acnt = (unsigned*)(ws + OFF_ACNT);
  float* mval = ws + OFF_MVAL;
  float* out = (float*)d_out;

  // zero cnt[16] + dcnt[16] + acnt (contiguous 33 words; minarr is inited
  // by prep itself — no big memset dispatch)
  hipMemsetAsync((void*)cnt, 0, 33 * sizeof(unsigned), stream);
  hipLaunchKernelGGL(prep_kernel, dim3(kPairs * kNP / 256), dim3(256), 0, stream,
                     rv, tgt, cpts, frec, minarr, cnt);
  hipLaunchKernelGGL(nn_kernel, dim3(kDirs * NQB * NCC), dim3(256), 0, stream,
                     cpts, frec, minarr, cnt, mval, dcnt, acnt, out);
}